// Round 2
// baseline (490.271 us; speedup 1.0000x reference)
//
#include <hip/hip_runtime.h>

#define OD 26
#define OH 122
#define OW 122
#define GS (128*128)
#define NOUT (OD*OH*OW)

// Stage 0: domain kernel dk[27] — voxel-independent, computed once.
__global__ void compute_dk_kernel(const float* __restrict__ dn,
                                  const float* __restrict__ dw0, const float* __restrict__ db0,
                                  const float* __restrict__ dw1, const float* __restrict__ db1,
                                  float* __restrict__ dk_out) {
    __shared__ float d0[125];
    int t = threadIdx.x;
    if (t < 125) {
        int tz = t / 25, ty = (t / 5) % 5, tx = t % 5;
        float acc = db0[0];
        #pragma unroll
        for (int kz = 0; kz < 3; ++kz)
            #pragma unroll
            for (int ky = 0; ky < 3; ++ky)
                #pragma unroll
                for (int kx = 0; kx < 3; ++kx)
                    acc += dw0[kz*9 + ky*3 + kx] *
                           dn[(1+tz+kz)*81 + (1+ty+ky)*9 + (1+tx+kx)];
        d0[t] = fmaxf(acc, 0.0f);
    }
    __syncthreads();
    if (t < 27) {
        int rz = t / 9, ry = (t / 3) % 3, rx = t % 3;
        float acc = db1[0];
        #pragma unroll
        for (int kz = 0; kz < 3; ++kz)
            #pragma unroll
            for (int ky = 0; ky < 3; ++ky)
                #pragma unroll
                for (int kx = 0; kx < 3; ++kx)
                    acc += dw1[kz*9 + ky*3 + kx] * d0[(rz+kz)*25 + (ry+ky)*5 + (rx+kx)];
        dk_out[t] = fmaxf(acc, 0.0f);
    }
}

// One thread per output voxel; rolling 3-slice t0 window + fused conv2.
// __launch_bounds__(64,4): 4 waves/SIMD -> VGPR budget 128 (live-set est ~120).
__global__ __launch_bounds__(64, 4) void jbf_main_kernel(
        const float* __restrict__ x, const float* __restrict__ guide,
        const float* __restrict__ rw0p, const float* __restrict__ rb0p,
        const float* __restrict__ rw1p, const float* __restrict__ rb1p,
        const float* __restrict__ dkp, float* __restrict__ out) {
    int idx = blockIdx.x * 64 + threadIdx.x;
    if (idx >= NOUT) return;
    int x0 = idx % OW;
    int y0 = (idx / OW) % OH;
    int z0 = idx / (OW * OH);

    // Wave-uniform weights -> s_load (scalar regs), verified by SGPR=96 in R1.
    float rw0[27], rw1[27];
    #pragma unroll
    for (int i = 0; i < 27; ++i) { rw0[i] = rw0p[i]; rw1[i] = rw1p[i]; }
    const float rb0 = rb0p[0], rb1 = rb1p[0];

    const float* gbase = guide + z0*GS + y0*128 + x0;
    const float gc = gbase[3*GS + 3*128 + 3];

    float t0[3][25];    // rolling z-window of conv1 slices (index = tz % 3)
    float acc[27];      // conv2 accumulators
    #pragma unroll
    for (int i = 0; i < 27; ++i) acc[i] = rb1;

    #pragma unroll
    for (int gz = 0; gz < 7; ++gz) {
        // A new conv1 slice tz==gz enters the window (only tz<=4 exist).
        if (gz <= 4) {
            const int sl = gz % 3;
            #pragma unroll
            for (int i = 0; i < 25; ++i) t0[sl][i] = rb0;
        }
        const float* gp = gbase + gz*GS;
        #pragma unroll
        for (int gy = 0; gy < 7; ++gy) {
            float s[7];
            #pragma unroll
            for (int j = 0; j < 7; ++j) s[j] = gp[gy*128 + j] - gc;
            // conv1: scatter this guide row into all (tz,ty) rows it feeds.
            #pragma unroll
            for (int kz = 0; kz < 3; ++kz) {
                const int tz = gz - kz;
                if (tz < 0 || tz > 4) continue;          // folds at compile time
                const int tsl = tz % 3;
                #pragma unroll
                for (int ky = 0; ky < 3; ++ky) {
                    const int ty = gy - ky;
                    if (ty < 0 || ty > 4) continue;      // folds at compile time
                    #pragma unroll
                    for (int tx = 0; tx < 5; ++tx)
                        #pragma unroll
                        for (int kx = 0; kx < 3; ++kx)
                            t0[tsl][ty*5 + tx] =
                                fmaf(rw0[kz*9 + ky*3 + kx], fabsf(s[tx + kx]),
                                     t0[tsl][ty*5 + tx]);
                }
            }
        }
        // Slice tzc = gz-2 is now complete: ReLU it and fold into conv2 accs,
        // then its registers are recycled for the slice entering at gz+1.
        const int tzc = gz - 2;
        if (tzc >= 0 && tzc <= 4) {
            const int csl = tzc % 3;
            #pragma unroll
            for (int i = 0; i < 25; ++i) t0[csl][i] = fmaxf(t0[csl][i], 0.0f);
            #pragma unroll
            for (int rz = 0; rz < 3; ++rz) {
                const int kz2 = tzc - rz;
                if (kz2 < 0 || kz2 > 2) continue;        // folds at compile time
                #pragma unroll
                for (int ry = 0; ry < 3; ++ry)
                    #pragma unroll
                    for (int rx = 0; rx < 3; ++rx)
                        #pragma unroll
                        for (int ky = 0; ky < 3; ++ky)
                            #pragma unroll
                            for (int kx = 0; kx < 3; ++kx)
                                acc[rz*9 + ry*3 + rx] =
                                    fmaf(rw1[kz2*9 + ky*3 + kx],
                                         t0[csl][(ry+ky)*5 + (rx+kx)],
                                         acc[rz*9 + ry*3 + rx]);
            }
        }
    }

    // Epilogue: domain*range weights, weighted average of the 3^3 x-patch.
    float num = 0.0f, den = 0.0f;
    const float* xb = x + (z0+2)*GS + (y0+2)*128 + (x0+2);
    #pragma unroll
    for (int rz = 0; rz < 3; ++rz)
        #pragma unroll
        for (int ry = 0; ry < 3; ++ry)
            #pragma unroll
            for (int rx = 0; rx < 3; ++rx) {
                const float w = dkp[rz*9 + ry*3 + rx] * fmaxf(acc[rz*9 + ry*3 + rx], 0.0f)
                                + 1e-10f;
                den += w;
                num = fmaf(w, xb[rz*GS + ry*128 + rx], num);
            }
    out[idx] = num / den;
}

extern "C" void kernel_launch(void* const* d_in, const int* in_sizes, int n_in,
                              void* d_out, int out_size, void* d_ws, size_t ws_size,
                              hipStream_t stream) {
    const float* x     = (const float*)d_in[0];
    const float* dn    = (const float*)d_in[1];
    const float* guide = (const float*)d_in[2];
    const float* rw0   = (const float*)d_in[3];
    const float* rb0   = (const float*)d_in[4];
    const float* rw1   = (const float*)d_in[5];
    const float* rb1   = (const float*)d_in[6];
    const float* dw0   = (const float*)d_in[7];
    const float* db0   = (const float*)d_in[8];
    const float* dw1   = (const float*)d_in[9];
    const float* db1   = (const float*)d_in[10];
    float* out = (float*)d_out;
    float* dk  = (float*)d_ws;   // 27 floats

    compute_dk_kernel<<<1, 128, 0, stream>>>(dn, dw0, db0, dw1, db1, dk);

    int nblk = (NOUT + 63) / 64;   // 6047 blocks of 64 -> fine-grained tail
    jbf_main_kernel<<<nblk, 64, 0, stream>>>(x, guide, rw0, rb0, rw1, rb1, dk, out);
}